// Round 1
// baseline (1093.212 us; speedup 1.0000x reference)
//
#include <hip/hip_runtime.h>
#include <math.h>

#define H 1024
#define Bb 64
#define L 2048
#define V 32000
#define P 128
#define NC 16
#define LC (L/NC)   // 128 l's per chunk

// ---------------- embedding gather ----------------
__global__ void k_embed(const int* __restrict__ seq, const float* __restrict__ emb,
                        float* __restrict__ x) {
  int b = blockIdx.x;
  int t = threadIdx.x;                 // 256 threads, H/4 = 256 float4
  long row = (long)seq[b];
  const float4* src = (const float4*)(emb + row * H);
  float4* dst = (float4*)(x + (size_t)b * H);
  dst[t] = src[t];
}

// ---------------- generic tiled skinny GEMM: C[64 x JT] = A[64 x K] * W[JT x K]^T ----------------
// TJ = columns per thread (2 or 4) -> JT = 16*TJ. ACT: 0=none, 1=tanh.
// Row mapping bb*16+tb / jj*16+tj keeps fragment reads at 2-way bank aliasing (free).
template<int TJ, int ACT>
__device__ __forceinline__ void gemm_tile(
    const float* __restrict__ A, int lda,
    const float* __restrict__ W, int ldw,   // W pre-offset to row j0
    const float* __restrict__ bias,         // pre-offset to j0
    float* __restrict__ C, int ldc,         // pre-offset to column j0
    int K)
{
  constexpr int JT = TJ * 16;
  __shared__ float As[64][36];   // stride 36 floats = 144 B (16B-aligned rows)
  __shared__ float Ws[JT][36];
  const int t  = threadIdx.x;
  const int tb = t & 15;         // b-group: b = bb*16 + tb
  const int tj = t >> 4;         // j-group: j = jj*16 + tj

  float acc[4][TJ];
#pragma unroll
  for (int i = 0; i < 4; ++i)
#pragma unroll
    for (int j = 0; j < TJ; ++j) acc[i][j] = 0.f;

  for (int k0 = 0; k0 < K; k0 += 32) {
    // stage A tile 64x32 (512 float4, 2 per thread)
#pragma unroll
    for (int r = 0; r < 2; ++r) {
      int i4 = r * 256 + t;
      int bi = i4 >> 3;
      int k4 = (i4 & 7) << 2;
      *(float4*)&As[bi][k4] = *(const float4*)(A + (size_t)bi * lda + k0 + k4);
    }
    // stage W tile JTx32
#pragma unroll
    for (int r = 0; r < JT/32; ++r) {
      int i4 = r * 256 + t;
      int ji = i4 >> 3;
      int k4 = (i4 & 7) << 2;
      *(float4*)&Ws[ji][k4] = *(const float4*)(W + (size_t)ji * ldw + k0 + k4);
    }
    __syncthreads();
#pragma unroll
    for (int ks = 0; ks < 32; ks += 4) {
      float4 av[4], wv[TJ];
#pragma unroll
      for (int bb = 0; bb < 4; ++bb) av[bb] = *(const float4*)&As[bb*16 + tb][ks];
#pragma unroll
      for (int jj = 0; jj < TJ; ++jj) wv[jj] = *(const float4*)&Ws[jj*16 + tj][ks];
#pragma unroll
      for (int bb = 0; bb < 4; ++bb)
#pragma unroll
        for (int jj = 0; jj < TJ; ++jj) {
          acc[bb][jj] += av[bb].x*wv[jj].x + av[bb].y*wv[jj].y
                       + av[bb].z*wv[jj].z + av[bb].w*wv[jj].w;
        }
    }
    __syncthreads();
  }
#pragma unroll
  for (int bb = 0; bb < 4; ++bb) {
    int b = bb*16 + tb;
#pragma unroll
    for (int jj = 0; jj < TJ; ++jj) {
      float v = acc[bb][jj] + bias[jj*16 + tj];
      if (ACT == 1) v = tanhf(v);
      C[(size_t)b * ldc + jj*16 + tj] = v;
    }
  }
}

// gi/gh gates: 192 blocks x 32 cols of the combined [x@W_ih^T | h@W_hh^T] (6H cols)
__global__ __launch_bounds__(256) void k_gates(
    const float* __restrict__ x, const float* __restrict__ h,
    const float* __restrict__ W_ih, const float* __restrict__ W_hh,
    const float* __restrict__ b_ih, const float* __restrict__ b_hh,
    float* __restrict__ gates)
{
  int j0 = blockIdx.x * 32;
  if (j0 < 3*H) {
    gemm_tile<2,0>(x, H, W_ih + (size_t)j0*H, H, b_ih + j0, gates + j0, 6*H, H);
  } else {
    int jh = j0 - 3*H;
    gemm_tile<2,0>(h, H, W_hh + (size_t)jh*H, H, b_hh + jh, gates + j0, 6*H, H);
  }
}

__global__ __launch_bounds__(256) void k_concat_gemm(
    const float* __restrict__ cat, const float* __restrict__ Wc,
    const float* __restrict__ bc, float* __restrict__ cat2)
{
  int j0 = blockIdx.x * 32;   // 32 blocks
  gemm_tile<2,1>(cat, 2*H, Wc + (size_t)j0*2*H, 2*H, bc + j0, cat2 + j0, H+P, 2*H);
}

__global__ __launch_bounds__(256) void k_out_gemm(
    const float* __restrict__ cat2, const float* __restrict__ Wo,
    const float* __restrict__ bo, float* __restrict__ out)
{
  int j0 = blockIdx.x * 64;   // 500 blocks
  gemm_tile<4,0>(cat2, H+P, Wo + (size_t)j0*(H+P), H+P, bo + j0, out + j0, V, H+P);
}

// ---------------- GRU gate combine ----------------
__global__ void k_gru_combine(const float* __restrict__ gates, const float* __restrict__ h,
                              float* __restrict__ cat, float* __restrict__ out_h) {
  int i = blockIdx.x * 256 + threadIdx.x;   // 65536
  int b = i >> 10, j = i & 1023;
  const float* g = gates + (size_t)b * 6 * H;
  float ir = g[j],       iz = g[j +   H], in_ = g[j + 2*H];
  float hr = g[j + 3*H], hz = g[j + 4*H], hn  = g[j + 5*H];
  float r = 1.f / (1.f + __expf(-(ir + hr)));
  float z = 1.f / (1.f + __expf(-(iz + hz)));
  float n = tanhf(in_ + r * hn);
  float hv = (1.f - z) * n + z * h[i];
  cat[(size_t)b * 2 * H + j] = hv;   // first half of concat input
  out_h[i] = hv;                     // h_new output
}

// ---------------- fused attention: wave-autonomous online-softmax ----------------
// Each wave owns full H (16 floats/lane), processes LC/4 = 32 l's with private
// (m,d,acc) state; XOR-butterfly reduce only (no block barriers in main loop);
// register double-buffer for the next l-pair's loads. One barrier at the end
// combines the 4 waves' partials.
__global__ __launch_bounds__(256) void k_energy(
    const float* __restrict__ cat, const float* __restrict__ enc,
    float* __restrict__ energies, float* __restrict__ part_m,
    float* __restrict__ part_d, float* __restrict__ part_vec)
{
  const int b = blockIdx.y;
  const int c = blockIdx.x;
  const int t = threadIdx.x;
  const int lane = t & 63, w = t >> 6;

  // hv slice: lane holds hv[j*256 + lane*4 .. +3], j = 0..3
  const float* hb = cat + (size_t)b * 2 * H + lane * 4;
  float4 hv[4];
#pragma unroll
  for (int j = 0; j < 4; ++j) hv[j] = *(const float4*)(hb + j*256);

  const int WL = LC / 4;                 // 32 l's per wave
  const int lbase = c * LC + w * WL;

  float m = -1e30f, d = 0.f;
  float4 acc[4];
#pragma unroll
  for (int j = 0; j < 4; ++j) acc[j] = make_float4(0.f, 0.f, 0.f, 0.f);

  // preload first pair
  float4 cv0[4], cv1[4];
  {
    const float* p0 = enc + ((size_t)lbase * Bb + b) * H + lane * 4;
    const float* p1 = p0 + (size_t)Bb * H;
#pragma unroll
    for (int j = 0; j < 4; ++j) { cv0[j] = *(const float4*)(p0 + j*256);
                                  cv1[j] = *(const float4*)(p1 + j*256); }
  }

  for (int li = 0; li < WL; li += 2) {
    // issue next pair's loads before the dependent chain
    float4 nv0[4], nv1[4];
    const bool more = (li + 2) < WL;
    if (more) {
      const float* p0 = enc + ((size_t)(lbase + li + 2) * Bb + b) * H + lane * 4;
      const float* p1 = p0 + (size_t)Bb * H;
#pragma unroll
      for (int j = 0; j < 4; ++j) { nv0[j] = *(const float4*)(p0 + j*256);
                                    nv1[j] = *(const float4*)(p1 + j*256); }
    }
    // two independent dot products (ILP)
    float p0 = 0.f, p1 = 0.f;
#pragma unroll
    for (int j = 0; j < 4; ++j) {
      p0 += hv[j].x*cv0[j].x + hv[j].y*cv0[j].y + hv[j].z*cv0[j].z + hv[j].w*cv0[j].w;
      p1 += hv[j].x*cv1[j].x + hv[j].y*cv1[j].y + hv[j].z*cv1[j].z + hv[j].w*cv1[j].w;
    }
    // XOR butterfly: all 64 lanes end with the full sum; two chains interleave
#pragma unroll
    for (int off = 1; off < 64; off <<= 1) {
      p0 += __shfl_xor(p0, off);
      p1 += __shfl_xor(p1, off);
    }
    if (lane == 0) {
      energies[(size_t)b * L + lbase + li]     = p0;
      energies[(size_t)b * L + lbase + li + 1] = p1;
    }
    // batched online-softmax update (one rescale per pair)
    float mn = fmaxf(m, fmaxf(p0, p1));
    float sc = __expf(m - mn);
    float w0 = __expf(p0 - mn);
    float w1 = __expf(p1 - mn);
    d = d * sc + w0 + w1;
#pragma unroll
    for (int j = 0; j < 4; ++j) {
      acc[j].x = acc[j].x*sc + w0*cv0[j].x + w1*cv1[j].x;
      acc[j].y = acc[j].y*sc + w0*cv0[j].y + w1*cv1[j].y;
      acc[j].z = acc[j].z*sc + w0*cv0[j].z + w1*cv1[j].z;
      acc[j].w = acc[j].w*sc + w0*cv0[j].w + w1*cv1[j].w;
    }
    m = mn;
    if (more) {
#pragma unroll
      for (int j = 0; j < 4; ++j) { cv0[j] = nv0[j]; cv1[j] = nv1[j]; }
    }
  }

  // combine the 4 waves' partials (single barrier)
  __shared__ float sm[4], sd[4];
  __shared__ float sacc[4][H];   // 16 KB
  if (lane == 0) { sm[w] = m; sd[w] = d; }
#pragma unroll
  for (int j = 0; j < 4; ++j) *(float4*)&sacc[w][j*256 + lane*4] = acc[j];
  __syncthreads();

  float M = fmaxf(fmaxf(sm[0], sm[1]), fmaxf(sm[2], sm[3]));
  float s0 = __expf(sm[0] - M), s1 = __expf(sm[1] - M);
  float s2 = __expf(sm[2] - M), s3 = __expf(sm[3] - M);
  float D = sd[0]*s0 + sd[1]*s1 + sd[2]*s2 + sd[3]*s3;

  float4 v0 = *(const float4*)&sacc[0][t*4];
  float4 v1 = *(const float4*)&sacc[1][t*4];
  float4 v2 = *(const float4*)&sacc[2][t*4];
  float4 v3 = *(const float4*)&sacc[3][t*4];
  float4 r;
  r.x = s0*v0.x + s1*v1.x + s2*v2.x + s3*v3.x;
  r.y = s0*v0.y + s1*v1.y + s2*v2.y + s3*v3.y;
  r.z = s0*v0.z + s1*v1.z + s2*v2.z + s3*v3.z;
  r.w = s0*v0.w + s1*v1.w + s2*v2.w + s3*v3.w;

  int pc = b * NC + c;
  if (t == 0) { part_m[pc] = M; part_d[pc] = D; }
  *(float4*)(part_vec + (size_t)pc * H + t * 4) = r;
}

__global__ void k_attn_combine(const float* __restrict__ part_m, const float* __restrict__ part_d,
                               const float* __restrict__ part_vec,
                               float* __restrict__ cat, float* __restrict__ MD) {
  int b = blockIdx.x, t = threadIdx.x;
  float M = -1e30f;
  for (int c = 0; c < NC; ++c) M = fmaxf(M, part_m[b*NC + c]);
  float D = 0.f;
  for (int c = 0; c < NC; ++c) D += part_d[b*NC + c] * __expf(part_m[b*NC + c] - M);
  float4 ctx = make_float4(0.f, 0.f, 0.f, 0.f);
  for (int c = 0; c < NC; ++c) {
    float s = __expf(part_m[b*NC + c] - M);
    float4 v = *(const float4*)(part_vec + (size_t)(b*NC + c) * H + t * 4);
    ctx.x += s*v.x; ctx.y += s*v.y; ctx.z += s*v.z; ctx.w += s*v.w;
  }
  float inv = 1.f / D;
  ctx.x *= inv; ctx.y *= inv; ctx.z *= inv; ctx.w *= inv;
  *(float4*)(cat + (size_t)b * 2 * H + H + t * 4) = ctx;   // second half of concat input
  if (t == 0) { MD[b*2] = M; MD[b*2+1] = D; }
}

__global__ void k_weights(const float* __restrict__ energies, const float* __restrict__ MD,
                          float* __restrict__ outw) {
  int i = blockIdx.x * 256 + threadIdx.x;   // 131072
  int b = i >> 11;
  outw[i] = __expf(energies[i] - MD[b*2]) / MD[b*2+1];
}

__global__ void k_prior(const float* __restrict__ prior, float* __restrict__ cat2) {
  int i = blockIdx.x * 256 + threadIdx.x;   // 8192
  int b = i >> 7, p = i & 127;
  cat2[(size_t)b * (H+P) + H + p] = prior[i];
}

extern "C" void kernel_launch(void* const* d_in, const int* in_sizes, int n_in,
                              void* d_out, int out_size, void* d_ws, size_t ws_size,
                              hipStream_t stream) {
  const int*   seq   = (const int*)  d_in[0];
  const float* hprev = (const float*)d_in[1];   // [1,B,H] == [B,H]
  const float* enc   = (const float*)d_in[2];   // [L,B,H]
  const float* prior = (const float*)d_in[3];   // [B,P]
  const float* emb   = (const float*)d_in[4];   // [V,H]
  const float* W_ih  = (const float*)d_in[5];
  const float* W_hh  = (const float*)d_in[6];
  const float* b_ih  = (const float*)d_in[7];
  const float* b_hh  = (const float*)d_in[8];
  const float* Wc    = (const float*)d_in[9];   // [H,2H]
  const float* bc    = (const float*)d_in[10];
  const float* Wo    = (const float*)d_in[11];  // [V,H+P]
  const float* bo    = (const float*)d_in[12];

  float* out   = (float*)d_out;                 // [B,V]
  float* out_h = out + (size_t)Bb * V;          // [1,B,H]
  float* out_w = out_h + (size_t)Bb * H;        // [B,1,L]

  float* ws    = (float*)d_ws;
  float* x     = ws;                  // 65536
  float* gates = x     + 65536;       // 393216 : [B][6H] = [gi | gh]
  float* cat   = gates + 393216;      // 131072 : [B][2H] = [h_new | ctx]
  float* cat2  = cat   + 131072;      //  73728 : [B][H+P] = [concat_out | prior]
  float* energ = cat2  + 73728;       // 131072
  float* pm    = energ + 131072;      //   1024
  float* pd    = pm    + 1024;        //   1024
  float* MD    = pd    + 1024;        //    128
  float* pvec  = MD    + 128;         // 1048576 : [B][NC][H]

  k_embed<<<Bb, 256, 0, stream>>>(seq, emb, x);
  k_gates<<<192, 256, 0, stream>>>(x, hprev, W_ih, W_hh, b_ih, b_hh, gates);
  k_gru_combine<<<256, 256, 0, stream>>>(gates, hprev, cat, out_h);
  k_prior<<<32, 256, 0, stream>>>(prior, cat2);
  dim3 eg(NC, Bb);
  k_energy<<<eg, 256, 0, stream>>>(cat, enc, energ, pm, pd, pvec);
  k_attn_combine<<<Bb, 256, 0, stream>>>(pm, pd, pvec, cat, MD);
  k_weights<<<512, 256, 0, stream>>>(energ, MD, out_w);
  k_concat_gemm<<<32, 256, 0, stream>>>(cat, Wc, bc, cat2);
  k_out_gemm<<<500, 256, 0, stream>>>(cat2, Wo, bo, out);
}

// Round 2
// 1067.725 us; speedup vs baseline: 1.0239x; 1.0239x over previous
//
#include <hip/hip_runtime.h>
#include <math.h>

#define H 1024
#define Bb 64
#define L 2048
#define V 32000
#define P 128
#define NC 16
#define LC (L/NC)   // 128 l's per chunk

// ---------------- generic tiled skinny GEMM: C[64 x JT] = A[64 x K] * W[JT x K]^T ----------------
// TJ = columns per thread -> JT = 16*TJ. ACT: 0=none, 1=tanh. EMB: indirect A rows via rows[].
// Double-buffered LDS staging: global->reg loads for step s+1 issued before compute of step s,
// reg->LDS store into the alternate buffer after compute, single barrier per step.
// Fragment row mapping bb*16+tb / jj*16+tj keeps fragment reads conflict-free (broadcast + distinct quads).
template<int TJ, int KSTEP, int ACT, bool EMB>
__device__ __forceinline__ void gemm_tile(
    const float* __restrict__ A, int lda, const int* __restrict__ rows,
    const float* __restrict__ W, int ldw,   // W pre-offset to row j0
    const float* __restrict__ bias,         // pre-offset to j0
    float* __restrict__ C, int ldc,         // pre-offset to column j0
    int K)
{
  constexpr int JT  = TJ * 16;
  constexpr int KS4 = KSTEP / 4;           // float4 per LDS row
  constexpr int AR  = (64 * KS4) / 256;    // A float4 per thread per step
  constexpr int WR  = (JT * KS4) / 256;    // W float4 per thread per step
  constexpr int LDSW = KSTEP + 4;          // pad: odd quad stride -> conflict-free fragments
  __shared__ float As[2][64][LDSW];
  __shared__ float Ws[2][JT][LDSW];
  const int t  = threadIdx.x;
  const int tb = t & 15;
  const int tj = t >> 4;

  // fixed per-thread staging coordinates (independent of step)
  int abi[AR], ak4[AR];
  const float* abase[AR];
#pragma unroll
  for (int r = 0; r < AR; ++r) {
    int i4 = r * 256 + t;
    abi[r] = i4 / KS4; ak4[r] = (i4 % KS4) * 4;
    const float* Ar = EMB ? (A + (size_t)rows[abi[r]] * lda) : (A + (size_t)abi[r] * lda);
    abase[r] = Ar + ak4[r];
  }
  int wji[WR], wk4[WR];
  const float* wbase[WR];
#pragma unroll
  for (int r = 0; r < WR; ++r) {
    int i4 = r * 256 + t;
    wji[r] = i4 / KS4; wk4[r] = (i4 % KS4) * 4;
    wbase[r] = W + (size_t)wji[r] * ldw + wk4[r];
  }

  float acc[4][TJ];
#pragma unroll
  for (int i = 0; i < 4; ++i)
#pragma unroll
    for (int j = 0; j < TJ; ++j) acc[i][j] = 0.f;

  float4 ra[AR], rw[WR];
  const int NS = K / KSTEP;

  // prologue: load + store step 0 into buf 0
#pragma unroll
  for (int r = 0; r < AR; ++r) ra[r] = *(const float4*)(abase[r]);
#pragma unroll
  for (int r = 0; r < WR; ++r) rw[r] = *(const float4*)(wbase[r]);
#pragma unroll
  for (int r = 0; r < AR; ++r) *(float4*)&As[0][abi[r]][ak4[r]] = ra[r];
#pragma unroll
  for (int r = 0; r < WR; ++r) *(float4*)&Ws[0][wji[r]][wk4[r]] = rw[r];
  __syncthreads();

  for (int s = 0; s < NS; ++s) {
    const int cb = s & 1;
    if (s + 1 < NS) {                       // issue next tile's global loads early
      const int off = (s + 1) * KSTEP;
#pragma unroll
      for (int r = 0; r < AR; ++r) ra[r] = *(const float4*)(abase[r] + off);
#pragma unroll
      for (int r = 0; r < WR; ++r) rw[r] = *(const float4*)(wbase[r] + off);
    }
#pragma unroll
    for (int ks = 0; ks < KSTEP; ks += 4) {
      float4 av[4], wv[TJ];
#pragma unroll
      for (int bb = 0; bb < 4; ++bb) av[bb] = *(const float4*)&As[cb][bb*16 + tb][ks];
#pragma unroll
      for (int jj = 0; jj < TJ; ++jj) wv[jj] = *(const float4*)&Ws[cb][jj*16 + tj][ks];
#pragma unroll
      for (int bb = 0; bb < 4; ++bb)
#pragma unroll
        for (int jj = 0; jj < TJ; ++jj) {
          acc[bb][jj] += av[bb].x*wv[jj].x + av[bb].y*wv[jj].y
                       + av[bb].z*wv[jj].z + av[bb].w*wv[jj].w;
        }
    }
    if (s + 1 < NS) {                       // write next tile into the other buffer
#pragma unroll
      for (int r = 0; r < AR; ++r) *(float4*)&As[cb^1][abi[r]][ak4[r]] = ra[r];
#pragma unroll
      for (int r = 0; r < WR; ++r) *(float4*)&Ws[cb^1][wji[r]][wk4[r]] = rw[r];
    }
    __syncthreads();
  }

#pragma unroll
  for (int bb = 0; bb < 4; ++bb) {
    int b = bb*16 + tb;
#pragma unroll
    for (int jj = 0; jj < TJ; ++jj) {
      float v = acc[bb][jj] + bias[jj*16 + tj];
      if (ACT == 1) v = tanhf(v);
      C[(size_t)b * ldc + jj*16 + tj] = v;
    }
  }
}

// gi/gh gates, embedding gather fused via indirect A rows: 192 blocks x 32 cols of [x@W_ih^T | h@W_hh^T]
__global__ __launch_bounds__(256) void k_gates(
    const int* __restrict__ seq, const float* __restrict__ emb,
    const float* __restrict__ h,
    const float* __restrict__ W_ih, const float* __restrict__ W_hh,
    const float* __restrict__ b_ih, const float* __restrict__ b_hh,
    float* __restrict__ gates)
{
  int j0 = blockIdx.x * 32;
  if (j0 < 3*H) {
    gemm_tile<2,64,0,true >(emb, H, seq, W_ih + (size_t)j0*H, H, b_ih + j0, gates + j0, 6*H, H);
  } else {
    int jh = j0 - 3*H;
    gemm_tile<2,64,0,false>(h, H, nullptr, W_hh + (size_t)jh*H, H, b_hh + jh, gates + j0, 6*H, H);
  }
}

__global__ __launch_bounds__(256) void k_concat_gemm(
    const float* __restrict__ cat, const float* __restrict__ Wc,
    const float* __restrict__ bc, float* __restrict__ cat2)
{
  int j0 = blockIdx.x * 16;   // 64 blocks
  gemm_tile<1,64,1,false>(cat, 2*H, nullptr, Wc + (size_t)j0*2*H, 2*H, bc + j0, cat2 + j0, H+P, 2*H);
}

__global__ __launch_bounds__(256) void k_out_gemm(
    const float* __restrict__ cat2, const float* __restrict__ Wo,
    const float* __restrict__ bo, float* __restrict__ out)
{
  int j0 = blockIdx.x * 64;   // 500 blocks
  gemm_tile<4,32,0,false>(cat2, H+P, nullptr, Wo + (size_t)j0*(H+P), H+P, bo + j0, out + j0, V, H+P);
}

// ---------------- GRU cell scalar ----------------
__device__ __forceinline__ float gru1(float ir, float iz, float in_,
                                      float hr, float hz, float hn, float hp) {
  float r = 1.f / (1.f + __expf(-(ir + hr)));
  float z = 1.f / (1.f + __expf(-(iz + hz)));
  float n = tanhf(in_ + r * hn);
  return (1.f - z) * n + z * hp;
}

// ---------------- fused GRU-combine + attention energies + online-softmax context partials -------
// Each block (b,c) recomputes h_new for its lane positions from gates (L2-hit after first block),
// then runs the wave-autonomous online-softmax over its 128 l's. Block c==0 (wave 0) also writes
// h_new to cat[:, 0:H] and out_h.
__global__ __launch_bounds__(256) void k_energy(
    const float* __restrict__ gates, const float* __restrict__ hprev,
    const float* __restrict__ enc,
    float* __restrict__ cat, float* __restrict__ out_h,
    float* __restrict__ energies, float* __restrict__ part_m,
    float* __restrict__ part_d, float* __restrict__ part_vec)
{
  const int b = blockIdx.y;
  const int c = blockIdx.x;
  const int t = threadIdx.x;
  const int lane = t & 63, w = t >> 6;

  // ---- fused GRU: hv[j4] = h_new[b][j4*256 + lane*4 .. +3] ----
  const float* g  = gates + (size_t)b * 6 * H;
  const float* hp = hprev + (size_t)b * H;
  float4 hv[4];
#pragma unroll
  for (int j4 = 0; j4 < 4; ++j4) {
    int j = j4*256 + lane*4;
    float4 ir  = *(const float4*)(g + j);
    float4 iz  = *(const float4*)(g + H   + j);
    float4 in_ = *(const float4*)(g + 2*H + j);
    float4 hr  = *(const float4*)(g + 3*H + j);
    float4 hz  = *(const float4*)(g + 4*H + j);
    float4 hn  = *(const float4*)(g + 5*H + j);
    float4 hpv = *(const float4*)(hp + j);
    hv[j4].x = gru1(ir.x, iz.x, in_.x, hr.x, hz.x, hn.x, hpv.x);
    hv[j4].y = gru1(ir.y, iz.y, in_.y, hr.y, hz.y, hn.y, hpv.y);
    hv[j4].z = gru1(ir.z, iz.z, in_.z, hr.z, hz.z, hn.z, hpv.z);
    hv[j4].w = gru1(ir.w, iz.w, in_.w, hr.w, hz.w, hn.w, hpv.w);
  }
  if (c == 0 && w == 0) {
#pragma unroll
    for (int j4 = 0; j4 < 4; ++j4) {
      *(float4*)(cat   + (size_t)b * 2 * H + j4*256 + lane*4) = hv[j4];
      *(float4*)(out_h + (size_t)b * H     + j4*256 + lane*4) = hv[j4];
    }
  }

  // ---- wave-autonomous online-softmax over this block's l-chunk ----
  const int WL = LC / 4;                 // 32 l's per wave
  const int lbase = c * LC + w * WL;

  float m = -1e30f, d = 0.f;
  float4 acc[4];
#pragma unroll
  for (int j = 0; j < 4; ++j) acc[j] = make_float4(0.f, 0.f, 0.f, 0.f);

  float4 cv0[4], cv1[4];
  {
    const float* p0 = enc + ((size_t)lbase * Bb + b) * H + lane * 4;
    const float* p1 = p0 + (size_t)Bb * H;
#pragma unroll
    for (int j = 0; j < 4; ++j) { cv0[j] = *(const float4*)(p0 + j*256);
                                  cv1[j] = *(const float4*)(p1 + j*256); }
  }

  for (int li = 0; li < WL; li += 2) {
    float4 nv0[4], nv1[4];
    const bool more = (li + 2) < WL;
    if (more) {
      const float* p0 = enc + ((size_t)(lbase + li + 2) * Bb + b) * H + lane * 4;
      const float* p1 = p0 + (size_t)Bb * H;
#pragma unroll
      for (int j = 0; j < 4; ++j) { nv0[j] = *(const float4*)(p0 + j*256);
                                    nv1[j] = *(const float4*)(p1 + j*256); }
    }
    float p0 = 0.f, p1 = 0.f;
#pragma unroll
    for (int j = 0; j < 4; ++j) {
      p0 += hv[j].x*cv0[j].x + hv[j].y*cv0[j].y + hv[j].z*cv0[j].z + hv[j].w*cv0[j].w;
      p1 += hv[j].x*cv1[j].x + hv[j].y*cv1[j].y + hv[j].z*cv1[j].z + hv[j].w*cv1[j].w;
    }
#pragma unroll
    for (int off = 1; off < 64; off <<= 1) {
      p0 += __shfl_xor(p0, off);
      p1 += __shfl_xor(p1, off);
    }
    if (lane == 0) {
      energies[(size_t)b * L + lbase + li]     = p0;
      energies[(size_t)b * L + lbase + li + 1] = p1;
    }
    float mn = fmaxf(m, fmaxf(p0, p1));
    float sc = __expf(m - mn);
    float w0 = __expf(p0 - mn);
    float w1 = __expf(p1 - mn);
    d = d * sc + w0 + w1;
#pragma unroll
    for (int j = 0; j < 4; ++j) {
      acc[j].x = acc[j].x*sc + w0*cv0[j].x + w1*cv1[j].x;
      acc[j].y = acc[j].y*sc + w0*cv0[j].y + w1*cv1[j].y;
      acc[j].z = acc[j].z*sc + w0*cv0[j].z + w1*cv1[j].z;
      acc[j].w = acc[j].w*sc + w0*cv0[j].w + w1*cv1[j].w;
    }
    m = mn;
    if (more) {
#pragma unroll
      for (int j = 0; j < 4; ++j) { cv0[j] = nv0[j]; cv1[j] = nv1[j]; }
    }
  }

  // combine the 4 waves' partials (single barrier)
  __shared__ float sm[4], sd[4];
  __shared__ float sacc[4][H];   // 16 KB
  if (lane == 0) { sm[w] = m; sd[w] = d; }
#pragma unroll
  for (int j = 0; j < 4; ++j) *(float4*)&sacc[w][j*256 + lane*4] = acc[j];
  __syncthreads();

  float M = fmaxf(fmaxf(sm[0], sm[1]), fmaxf(sm[2], sm[3]));
  float s0 = __expf(sm[0] - M), s1 = __expf(sm[1] - M);
  float s2 = __expf(sm[2] - M), s3 = __expf(sm[3] - M);
  float D = sd[0]*s0 + sd[1]*s1 + sd[2]*s2 + sd[3]*s3;

  float4 v0 = *(const float4*)&sacc[0][t*4];
  float4 v1 = *(const float4*)&sacc[1][t*4];
  float4 v2 = *(const float4*)&sacc[2][t*4];
  float4 v3 = *(const float4*)&sacc[3][t*4];
  float4 r;
  r.x = s0*v0.x + s1*v1.x + s2*v2.x + s3*v3.x;
  r.y = s0*v0.y + s1*v1.y + s2*v2.y + s3*v3.y;
  r.z = s0*v0.z + s1*v1.z + s2*v2.z + s3*v3.z;
  r.w = s0*v0.w + s1*v1.w + s2*v2.w + s3*v3.w;

  int pc = b * NC + c;
  if (t == 0) { part_m[pc] = M; part_d[pc] = D; }
  *(float4*)(part_vec + (size_t)pc * H + t * 4) = r;
}

// ---------------- attention combine + softmax weights output + prior copy (fused) ---------------
__global__ void k_attn_combine(const float* __restrict__ part_m, const float* __restrict__ part_d,
                               const float* __restrict__ part_vec,
                               const float* __restrict__ energies, const float* __restrict__ prior,
                               float* __restrict__ cat, float* __restrict__ cat2,
                               float* __restrict__ outw) {
  int b = blockIdx.x, t = threadIdx.x;
  float M = -1e30f;
  for (int c = 0; c < NC; ++c) M = fmaxf(M, part_m[b*NC + c]);
  float D = 0.f;
  for (int c = 0; c < NC; ++c) D += part_d[b*NC + c] * __expf(part_m[b*NC + c] - M);
  float4 ctx = make_float4(0.f, 0.f, 0.f, 0.f);
  for (int c = 0; c < NC; ++c) {
    float s = __expf(part_m[b*NC + c] - M);
    float4 v = *(const float4*)(part_vec + (size_t)(b*NC + c) * H + t * 4);
    ctx.x += s*v.x; ctx.y += s*v.y; ctx.z += s*v.z; ctx.w += s*v.w;
  }
  float inv = 1.f / D;
  ctx.x *= inv; ctx.y *= inv; ctx.z *= inv; ctx.w *= inv;
  *(float4*)(cat + (size_t)b * 2 * H + H + t * 4) = ctx;   // second half of concat input

  if (t < P) cat2[(size_t)b * (H+P) + H + t] = prior[b*P + t];   // prior copy

  const float* eb = energies + (size_t)b * L;
  float* ob = outw + (size_t)b * L;
#pragma unroll
  for (int i = t; i < L; i += 256) ob[i] = __expf(eb[i] - M) * inv;  // softmax weights
}

extern "C" void kernel_launch(void* const* d_in, const int* in_sizes, int n_in,
                              void* d_out, int out_size, void* d_ws, size_t ws_size,
                              hipStream_t stream) {
  const int*   seq   = (const int*)  d_in[0];
  const float* hprev = (const float*)d_in[1];   // [1,B,H] == [B,H]
  const float* enc   = (const float*)d_in[2];   // [L,B,H]
  const float* prior = (const float*)d_in[3];   // [B,P]
  const float* emb   = (const float*)d_in[4];   // [V,H]
  const float* W_ih  = (const float*)d_in[5];
  const float* W_hh  = (const float*)d_in[6];
  const float* b_ih  = (const float*)d_in[7];
  const float* b_hh  = (const float*)d_in[8];
  const float* Wc    = (const float*)d_in[9];   // [H,2H]
  const float* bc    = (const float*)d_in[10];
  const float* Wo    = (const float*)d_in[11];  // [V,H+P]
  const float* bo    = (const float*)d_in[12];

  float* out   = (float*)d_out;                 // [B,V]
  float* out_h = out + (size_t)Bb * V;          // [1,B,H]
  float* out_w = out_h + (size_t)Bb * H;        // [B,1,L]

  float* ws    = (float*)d_ws;
  float* gates = ws;                  // 393216 : [B][6H] = [gi | gh]
  float* cat   = gates + 393216;      // 131072 : [B][2H] = [h_new | ctx]
  float* cat2  = cat   + 131072;      //  73728 : [B][H+P] = [concat_out | prior]
  float* energ = cat2  + 73728;       // 131072
  float* pm    = energ + 131072;      //   1024
  float* pd    = pm    + 1024;        //   1024
  float* pvec  = pd    + 1024;        // 1048576 : [B][NC][H]

  k_gates<<<192, 256, 0, stream>>>(seq, emb, hprev, W_ih, W_hh, b_ih, b_hh, gates);
  dim3 eg(NC, Bb);
  k_energy<<<eg, 256, 0, stream>>>(gates, hprev, enc, cat, out_h, energ, pm, pd, pvec);
  k_attn_combine<<<Bb, 256, 0, stream>>>(pm, pd, pvec, energ, prior, cat, cat2, out_w);
  k_concat_gemm<<<64, 256, 0, stream>>>(cat, Wc, bc, cat2);
  k_out_gemm<<<500, 256, 0, stream>>>(cat2, Wo, bo, out);
}